// Round 3
// baseline (674.272 us; speedup 1.0000x reference)
//
#include <hip/hip_runtime.h>
#include <hip/hip_bf16.h>
#include <cstdint>
#include <cstddef>

typedef __bf16 bf16x8 __attribute__((ext_vector_type(8)));
typedef float f32x4 __attribute__((ext_vector_type(4)));
typedef short s16x4 __attribute__((ext_vector_type(4)));
typedef unsigned short u16;
typedef unsigned int u32;
typedef unsigned short u16x8 __attribute__((ext_vector_type(8)));

#define ROWS 32768       // B*T*S
#define DMODEL 1024
#define NQKV 1536        // H*HD + 2*KVH*HD
// folded softcap constants: logits z = dot*rq*rk*0.125, capped = 50*tanh(z/50)
//   e2 = exp2(dot*rq*rk * C1),  C1 = 2*0.125/50*log2(e)
//   p  = exp2(B2 - A2 * rcp(e2+1)),  A2 = 100*log2(e), B2 = 50*log2(e)
#define C1_ 0.0072134752044448170f
#define A2_ 144.26950408889634f
#define B2_ 72.13475204444817f

__device__ __forceinline__ u16 f2bf(float f) {
    unsigned u = __float_as_uint(f);
    u += 0x7fffu + ((u >> 16) & 1u);   // RNE
    return (u16)(u >> 16);
}
__device__ __forceinline__ float bf_lo(u32 u) { return __uint_as_float(u << 16); }
__device__ __forceinline__ float bf_hi(u32 u) { return __uint_as_float(u & 0xffff0000u); }
__device__ __forceinline__ u32 pack_rne(float lo, float hi) {
    return (u32)f2bf(lo) | ((u32)f2bf(hi) << 16);
}
// packed f32x2 -> bf16x2 (v_cvt_pk_bf16_f32 on gfx950), RNE
__device__ __forceinline__ u32 pk2(float lo, float hi) {
    union { __hip_bfloat162 b; u32 u; } c;
    c.b = __float22bfloat162_rn(float2{lo, hi});
    return c.u;
}

// ---------------- elementwise f32 -> bf16 (x) ----------------
__global__ __launch_bounds__(256) void f32_to_bf16_vec(
    const float* __restrict__ in, u16* __restrict__ out, int n4)
{
    int i = blockIdx.x * 256 + threadIdx.x;
    if (i >= n4) return;
    float4 f = ((const float4*)in)[i];
    ushort4 u;
    u.x = f2bf(f.x); u.y = f2bf(f.y); u.z = f2bf(f.z); u.w = f2bf(f.w);
    ((ushort4*)out)[i] = u;
}

// ---------------- transpose f32 [R][C] -> bf16 [C][R] ----------------
__global__ __launch_bounds__(256) void transpose_bf16(
    const float* __restrict__ src, u16* __restrict__ dst, int R, int C)
{
    __shared__ float tile[32][33];
    int c0 = blockIdx.x * 32;
    int r0 = blockIdx.y * 32;
    int tx = threadIdx.x & 31;
    int ty = threadIdx.x >> 5;        // 0..7
#pragma unroll
    for (int i = 0; i < 32; i += 8)
        tile[ty + i][tx] = src[(size_t)(r0 + ty + i) * C + (c0 + tx)];
    __syncthreads();
#pragma unroll
    for (int i = 0; i < 32; i += 8)
        dst[(size_t)(c0 + ty + i) * R + (r0 + tx)] = f2bf(tile[tx][ty + i]);
}

// ---------------- MFMA GEMM: A[M][K] bf16 @ Bt[N][K] bf16 -> C[M][N] ----------------
template<bool BF16OUT>
__global__ __launch_bounds__(256) void gemm_bt(
    const u16* __restrict__ A, const u16* __restrict__ Bt,
    void* __restrict__ Cout, int M, int N, int K)
{
    __shared__ u16 As[128][32];
    __shared__ u16 Bs[128][32];
    const int tid  = threadIdx.x;
    const int wave = tid >> 6;
    const int lane = tid & 63;
    const int q4   = lane >> 4;
    const int cl   = lane & 15;
    const int wr   = wave >> 1, wc = wave & 1;
    const int m0   = blockIdx.x * 128;
    const int n0   = blockIdx.y * 128;
    const int srow = lane >> 2;          // 0..15
    const int skoff = (lane & 3) * 8;    // elements

    const f32x4 zero = {0.f, 0.f, 0.f, 0.f};
    f32x4 acc[4][4];
#pragma unroll
    for (int i = 0; i < 4; ++i)
#pragma unroll
        for (int j = 0; j < 4; ++j) acc[i][j] = zero;

    for (int k0 = 0; k0 < K; k0 += 32) {
        __syncthreads();
#pragma unroll
        for (int cc = 0; cc < 2; ++cc) {
            int r = 32 * wave + 16 * cc + srow;
            const u16* ga = A + (size_t)(m0 + r) * K + k0 + skoff;
            __builtin_amdgcn_global_load_lds(
                (const __attribute__((address_space(1))) void*)ga,
                (__attribute__((address_space(3))) void*)(&As[32 * wave + 16 * cc][0]),
                16, 0, 0);
            const u16* gb = Bt + (size_t)(n0 + r) * K + k0 + skoff;
            __builtin_amdgcn_global_load_lds(
                (const __attribute__((address_space(1))) void*)gb,
                (__attribute__((address_space(3))) void*)(&Bs[32 * wave + 16 * cc][0]),
                16, 0, 0);
        }
        __syncthreads();
        bf16x8 af[4], bfr[4];
#pragma unroll
        for (int i = 0; i < 4; ++i)
            af[i] = *(const bf16x8*)&As[64 * wr + 16 * i + cl][q4 * 8];
#pragma unroll
        for (int j = 0; j < 4; ++j)
            bfr[j] = *(const bf16x8*)&Bs[64 * wc + 16 * j + cl][q4 * 8];
#pragma unroll
        for (int i = 0; i < 4; ++i)
#pragma unroll
            for (int j = 0; j < 4; ++j)
                acc[i][j] = __builtin_amdgcn_mfma_f32_16x16x32_bf16(
                    af[i], bfr[j], acc[i][j], 0, 0, 0);
    }

#pragma unroll
    for (int i = 0; i < 4; ++i)
#pragma unroll
        for (int j = 0; j < 4; ++j)
#pragma unroll
            for (int r = 0; r < 4; ++r) {
                int row = m0 + 64 * wr + 16 * i + q4 * 4 + r;
                int col = n0 + 64 * wc + 16 * j + cl;
                if (BF16OUT)
                    ((u16*)Cout)[(size_t)row * N + col] = f2bf(acc[i][j][r]);
                else
                    ((float*)Cout)[(size_t)row * N + col] = acc[i][j][r];
            }
}

// ---------------- fused attention, 1 block per (bt, h) ----------------
// 4 waves x 64 Q-rows. S^T = K@Q^T (C-layout col=q) feeds PV directly:
// C-layout of S^T == B-operand layout of 16x16x16 mfma, so P never leaves
// registers (no LDS round-trip, no in-loop barrier). O^T = V^T @ P^T.
// Fixed-max softmax (softcap bounds logits); l via ones-MFMA; QK rmsnorm fused.
__global__ __launch_bounds__(256, 3) void attention_kernel(
    const u16* __restrict__ qkv, const float* __restrict__ qw,
    const float* __restrict__ kw, u16* __restrict__ ao)
{
    const int bi  = blockIdx.x;
    const int bt  = bi >> 4;
    const int h   = bi & 15;
    const int kvh = h >> 2;          // GROUPS=4
    const int tid  = threadIdx.x;
    const int wave = tid >> 6;
    const int lane = tid & 63;
    const int q4   = lane >> 4;
    const int cl   = lane & 15;

    __shared__ __align__(16) u16 Vt[64][264];   // V^T only; 33792 B

    // stage V^T: thread t owns source row s=t (64 bf16)
    {
        const u16* vrow = qkv + (size_t)(bt * 256 + tid) * NQKV + 1280 + kvh * 64;
#pragma unroll
        for (int ch = 0; ch < 8; ++ch) {
            u16x8 v8 = *(const u16x8*)(vrow + ch * 8);
#pragma unroll
            for (int e = 0; e < 8; ++e) Vt[ch * 8 + e][tid] = v8[e];
        }
    }
    __syncthreads();

    const u16* qbase = qkv + (size_t)(bt * 256) * NQKV + h * 64;
    const u16* kbase = qkv + (size_t)(bt * 256) * NQKV + 1024 + kvh * 64;

    // ---- hoist Q fragments (B-operand layout): load, rms, scale by wq*wk ----
    uint4 qa[2][4];          // [ks][qi], each = bf16x8; lane cl holds Q-row 16qi+cl
    float rq[4];
    float wqk[2][8];
#pragma unroll
    for (int ks = 0; ks < 2; ++ks)
#pragma unroll
        for (int e = 0; e < 8; ++e) {
            int d = ks * 32 + q4 * 8 + e;
            wqk[ks][e] = qw[d] * kw[d];
        }
#pragma unroll
    for (int qi = 0; qi < 4; ++qi) {
#pragma unroll
        for (int ks = 0; ks < 2; ++ks)
            qa[ks][qi] = *(const uint4*)(qbase +
                (size_t)(wave * 64 + 16 * qi + cl) * NQKV + ks * 32 + q4 * 8);
        float ss = 0.f;
#pragma unroll
        for (int ks = 0; ks < 2; ++ks) {
            const u32* u = (const u32*)&qa[ks][qi];
#pragma unroll
            for (int e = 0; e < 4; ++e) {
                float lo = bf_lo(u[e]), hi = bf_hi(u[e]);
                ss += lo * lo + hi * hi;
            }
        }
        ss += __shfl_xor(ss, 16, 64);
        ss += __shfl_xor(ss, 32, 64);
        rq[qi] = rsqrtf(ss * (1.0f / 64.0f) + 1e-6f);
        // apply wq*wk element-wise (exact when w==1: repack of unchanged bf16)
#pragma unroll
        for (int ks = 0; ks < 2; ++ks) {
            u32* u = (u32*)&qa[ks][qi];
#pragma unroll
            for (int e = 0; e < 4; ++e) {
                float lo = bf_lo(u[e]) * wqk[ks][2 * e];
                float hi = bf_hi(u[e]) * wqk[ks][2 * e + 1];
                u[e] = pack_rne(lo, hi);
            }
        }
    }

    const f32x4 zero = {0.f, 0.f, 0.f, 0.f};
    f32x4 o[4][4];           // [dj][qi]: O[q=16qi+cl][d=16dj+4q4+r]
    f32x4 lacc[4];           // [qi]: all rows = l[q=16qi+cl]
#pragma unroll
    for (int dj = 0; dj < 4; ++dj) {
        lacc[dj] = zero;
#pragma unroll
        for (int qi = 0; qi < 4; ++qi) o[dj][qi] = zero;
    }
    s16x4 ones16;
#pragma unroll
    for (int e = 0; e < 4; ++e) ones16[e] = (short)0x3F80;   // bf16 1.0

#pragma unroll
    for (int nb = 0; nb < 4; ++nb) {
#pragma unroll
        for (int si = 0; si < 4; ++si) {
            // K fragment (A-operand layout): lane cl holds K-row 16si+cl
            uint4 kb0 = *(const uint4*)(kbase +
                (size_t)(nb * 64 + 16 * si + cl) * NQKV + q4 * 8);
            uint4 kb1 = *(const uint4*)(kbase +
                (size_t)(nb * 64 + 16 * si + cl) * NQKV + 32 + q4 * 8);
            float ss = 0.f;
            {
                const u32* u0 = (const u32*)&kb0;
                const u32* u1 = (const u32*)&kb1;
#pragma unroll
                for (int e = 0; e < 4; ++e) {
                    float a = bf_lo(u0[e]), b = bf_hi(u0[e]);
                    float c = bf_lo(u1[e]), d = bf_hi(u1[e]);
                    ss += a * a + b * b + c * c + d * d;
                }
            }
            ss += __shfl_xor(ss, 16, 64);
            ss += __shfl_xor(ss, 32, 64);
            float rk = rsqrtf(ss * (1.0f / 64.0f) + 1e-6f);
            // redistribute rk to C-layout rows (s-row = 4*q4+r)
            float cr[4];
#pragma unroll
            for (int r = 0; r < 4; ++r)
                cr[r] = __shfl(rk, 4 * q4 + r, 64) * C1_;

            // S^T tiles: D[s'][q], col=cl=q (rq in place), row=4q4+r=s'
            f32x4 st[4];
#pragma unroll
            for (int qi = 0; qi < 4; ++qi) {
                st[qi] = __builtin_amdgcn_mfma_f32_16x16x32_bf16(
                    *(const bf16x8*)&kb0, *(const bf16x8*)&qa[0][qi], zero, 0, 0, 0);
                st[qi] = __builtin_amdgcn_mfma_f32_16x16x32_bf16(
                    *(const bf16x8*)&kb1, *(const bf16x8*)&qa[1][qi], st[qi], 0, 0, 0);
            }

            // softcap+exp, pack to B-operand frags of 16x16x16 (k=4q4+j == row)
            s16x4 pf[4];
#pragma unroll
            for (int qi = 0; qi < 4; ++qi) {
                float p[4];
#pragma unroll
                for (int r = 0; r < 4; ++r) {
                    float e2 = __builtin_amdgcn_exp2f(st[qi][r] * rq[qi] * cr[r]);
                    float rc = __builtin_amdgcn_rcpf(e2 + 1.0f);
                    p[r] = __builtin_amdgcn_exp2f(fmaf(-A2_, rc, B2_));
                }
                union { u32 u[2]; s16x4 s; } pkd;
                pkd.u[0] = pk2(p[0], p[1]);
                pkd.u[1] = pk2(p[2], p[3]);
                pf[qi] = pkd.s;
            }

            // l += ones @ P^T
#pragma unroll
            for (int qi = 0; qi < 4; ++qi)
                lacc[qi] = __builtin_amdgcn_mfma_f32_16x16x16bf16_1k(
                    ones16, pf[qi], lacc[qi], 0, 0, 0);

            // O^T += V^T @ P^T  (A = V^T frag from LDS, 8B reads)
#pragma unroll
            for (int dj = 0; dj < 4; ++dj) {
                s16x4 vf = *(const s16x4*)&Vt[16 * dj + cl][nb * 64 + 16 * si + 4 * q4];
#pragma unroll
                for (int qi = 0; qi < 4; ++qi)
                    o[dj][qi] = __builtin_amdgcn_mfma_f32_16x16x16bf16_1k(
                        vf, pf[qi], o[dj][qi], 0, 0, 0);
            }
        }
    }

    // normalize + store: lane owns row q=16qi+cl, 4 consecutive d per dj -> 8B stores
#pragma unroll
    for (int qi = 0; qi < 4; ++qi) {
        float inv = __builtin_amdgcn_rcpf(lacc[qi][0]);
        int row = bt * 256 + wave * 64 + 16 * qi + cl;
        u16* orow = ao + (size_t)row * DMODEL + h * 64 + 4 * q4;
#pragma unroll
        for (int dj = 0; dj < 4; ++dj) {
            uint2 w;
            w.x = pk2(o[dj][qi][0] * inv, o[dj][qi][1] * inv);
            w.y = pk2(o[dj][qi][2] * inv, o[dj][qi][3] * inv);
            *(uint2*)(orow + 16 * dj) = w;
        }
    }
}

// ---------------- host launch ----------------
extern "C" void kernel_launch(void* const* d_in, const int* in_sizes, int n_in,
                              void* d_out, int out_size, void* d_ws, size_t ws_size,
                              hipStream_t stream)
{
    const float* x  = (const float*)d_in[0];
    const float* Wq = (const float*)d_in[1];
    const float* Wk = (const float*)d_in[2];
    const float* Wv = (const float*)d_in[3];
    const float* Wo = (const float*)d_in[4];
    const float* qw = (const float*)d_in[5];
    const float* kw = (const float*)d_in[6];
    float* out = (float*)d_out;

    char* ws = (char*)d_ws;
    u16* Xb  = (u16*)(ws);                            // 32768x1024 bf16 (64 MB)
    u16* QKV = (u16*)(ws + (size_t)67108864);         // 32768x1536 bf16 (96 MB)
    u16* AO  = (u16*)(ws + (size_t)167772160);        // 32768x1024 bf16 (64 MB)
    u16* WcT = (u16*)(ws + (size_t)234881024);        // 1536x1024 bf16  (3 MB)
    u16* WoT = (u16*)(ws + (size_t)238026752);        // 1024x1024 bf16  (2 MB)

    // x -> bf16
    f32_to_bf16_vec<<<dim3(32768), dim3(256), 0, stream>>>(x, Xb, 8388608);
    // W^T (concatenated q|k|v) and Wo^T, bf16
    transpose_bf16<<<dim3(32, 32), dim3(256), 0, stream>>>(Wq, WcT, 1024, 1024);
    transpose_bf16<<<dim3(8, 32), dim3(256), 0, stream>>>(Wk, WcT + (size_t)1024 * 1024, 1024, 256);
    transpose_bf16<<<dim3(8, 32), dim3(256), 0, stream>>>(Wv, WcT + (size_t)1280 * 1024, 1024, 256);
    transpose_bf16<<<dim3(32, 32), dim3(256), 0, stream>>>(Wo, WoT, 1024, 1024);
    // QKV projection (q,k unnormalized; attention fuses rmsnorm)
    gemm_bt<true><<<dim3(256, 12), dim3(256), 0, stream>>>(Xb, WcT, (void*)QKV, ROWS, NQKV, 1024);
    // attention
    attention_kernel<<<dim3(2048), dim3(256), 0, stream>>>(QKV, qw, kw, AO);
    // output projection -> fp32 d_out
    gemm_bt<false><<<dim3(256, 8), dim3(256), 0, stream>>>(AO, WoT, (void*)out, ROWS, DMODEL, 1024);
}